// Round 9
// baseline (239.273 us; speedup 1.0000x reference)
//
#include <hip/hip_runtime.h>

// B=8, T=1024, D=512, H=8, dh=64.
// bf16 MFMA pipeline: prep -> wconv -> Wkv^T (gemm64) -> batched q/k/v proj -> flash attention
// (r6 structure + XCD grid, fused result-mean) -> ffn1 fused relu+column-mean -> ffn2 wide.
// r9: proj3/ffn1 use 256x128 M-doubled tiles (4 waves x 128x64, acc[8][4]) to halve
// barrier/staging cost per FLOP at short K=512 (these ran at ~300 TF with 128x128).
// LESSONS: attn LDS <= 64KB/block (r7); gemm-family launch_bounds plain (256) — no min-wave cap.

typedef __bf16 bf16x8 __attribute__((ext_vector_type(8)));
typedef __bf16 bf16x4 __attribute__((ext_vector_type(4)));
typedef float f32x4 __attribute__((ext_vector_type(4)));
typedef unsigned short u16x8 __attribute__((ext_vector_type(8)));
typedef unsigned short u16x4 __attribute__((ext_vector_type(4)));

#define MFMA_BF16(a, b, c) __builtin_amdgcn_mfma_f32_16x16x32_bf16((a), (b), (c), 0, 0, 0)
#define NEGBIG (-4294967295.0f)
#define QSCALE 0.18033688011112042f   // 0.125 * log2(e)
#define EXP2(x) __builtin_amdgcn_exp2f(x)

#define GLL16(g, l)                                                                 \
    __builtin_amdgcn_global_load_lds((__attribute__((address_space(1))) void*)(g),  \
                                     (__attribute__((address_space(3))) void*)(l),  \
                                     16, 0, 0)

static __device__ __forceinline__ unsigned short f2bf(float f) {
    __bf16 h = (__bf16)f;
    return __builtin_bit_cast(unsigned short, h);
}
static __device__ __forceinline__ float bf2f(unsigned short h) {
    return __builtin_bit_cast(float, ((unsigned int)h) << 16);
}

// ---------------- prep: q_in = queries + pos*sqrt(512), k_in = keys + pos*sqrt(512) ----------
__global__ __launch_bounds__(256) void prep_kernel(
    const float* __restrict__ q, const float* __restrict__ k,
    const float* __restrict__ pos,
    unsigned short* __restrict__ qo, unsigned short* __restrict__ ko)
{
    size_t i = ((size_t)blockIdx.x * 256 + threadIdx.x) * 4;
    size_t td = i & (size_t)(1024 * 512 - 1);
    float4 qv = *(const float4*)(q + i);
    float4 kv = *(const float4*)(k + i);
    float4 pv = *(const float4*)(pos + td);
    const float S = 22.627416997969522f;
    u16x4 qr, kr;
    qr[0] = f2bf(qv.x + pv.x * S); qr[1] = f2bf(qv.y + pv.y * S);
    qr[2] = f2bf(qv.z + pv.z * S); qr[3] = f2bf(qv.w + pv.w * S);
    kr[0] = f2bf(kv.x + pv.x * S); kr[1] = f2bf(kv.y + pv.y * S);
    kr[2] = f2bf(kv.z + pv.z * S); kr[3] = f2bf(kv.w + pv.w * S);
    *(u16x4*)(qo + i) = qr;
    *(u16x4*)(ko + i) = kr;
}

// ---------------- weight transpose + cast, exact 1D grid (2816 blocks) -----------------------
__global__ __launch_bounds__(256) void wconv_kernel(
    const float* __restrict__ w0, const float* __restrict__ w1, const float* __restrict__ w2,
    const float* __restrict__ w3, const float* __restrict__ w4,
    unsigned short* __restrict__ o0, unsigned short* __restrict__ o1, unsigned short* __restrict__ o2,
    unsigned short* __restrict__ o3, unsigned short* __restrict__ o4,
    unsigned short* __restrict__ wkp)
{
    int id = blockIdx.x;
    const float* in; unsigned short* out; int K, N, kt, nt; bool dup = false;
    if (id < 768) {
        int m = id >> 8; id &= 255;
        in  = (m == 0) ? w0 : ((m == 1) ? w1 : w2);
        out = (m == 0) ? o0 : ((m == 1) ? o1 : o2);
        dup = (m == 1);
        K = 512; N = 512; kt = id >> 4; nt = id & 15;
    } else if (id < 1792) {
        id -= 768; in = w3; out = o3; K = 512; N = 2048; kt = id >> 6; nt = id & 63;
    } else {
        id -= 1792; in = w4; out = o4; K = 2048; N = 512; kt = id >> 4; nt = id & 15;
    }
    int k0 = kt * 32, n0 = nt * 32;
    __shared__ float tile[32][33];
    int tx = threadIdx.x & 31, ty = threadIdx.x >> 5;
#pragma unroll
    for (int i = 0; i < 32; i += 8) {
        float v = in[(size_t)(k0 + ty + i) * N + n0 + tx];
        tile[ty + i][tx] = v;
        if (dup) wkp[(size_t)(k0 + ty + i) * 512 + n0 + tx] = f2bf(v);
    }
    __syncthreads();
#pragma unroll
    for (int i = 0; i < 32; i += 8)
        out[(size_t)(n0 + ty + i) * K + k0 + tx] = f2bf(tile[tx][ty + i]);
}

// ---------------- small GEMM, 64x64 tiles (Wkv^T = Wv^T * Wk): grid (8,8) -------------------
__global__ __launch_bounds__(256) void gemm64(
    const unsigned short* __restrict__ A, const unsigned short* __restrict__ Bt,
    unsigned short* __restrict__ C, int N, int K)
{
    __shared__ unsigned short As[64 * 32];
    __shared__ unsigned short Bs[64 * 32];
    const int tid = threadIdx.x;
    const int wave = tid >> 6, lane = tid & 63;
    const int g = lane >> 4, lr = lane & 15;
    const int wm = (wave >> 1) * 32, wn = (wave & 1) * 32;
    const size_t bm = (size_t)blockIdx.x * 64, bn = (size_t)blockIdx.y * 64;
    const int row = tid >> 2, kc = (tid & 3) * 8;
    const unsigned short* Ap = A + (bm + row) * (size_t)K + kc;
    const unsigned short* Bp = Bt + (bn + row) * (size_t)K + kc;
    unsigned short* AsW = As + tid * 8;
    unsigned short* BsW = Bs + tid * 8;

    f32x4 acc[2][2] = {};
    for (int k0 = 0; k0 < K; k0 += 32) {
        __syncthreads();
        GLL16(Ap + k0, AsW);
        GLL16(Bp + k0, BsW);
        __syncthreads();
        bf16x8 af[2], bfr[2];
#pragma unroll
        for (int t = 0; t < 2; ++t) {
            af[t]  = *(const bf16x8*)&As[(wm + t * 16 + lr) * 32 + g * 8];
            bfr[t] = *(const bf16x8*)&Bs[(wn + t * 16 + lr) * 32 + g * 8];
        }
#pragma unroll
        for (int i = 0; i < 2; ++i)
#pragma unroll
            for (int j = 0; j < 2; ++j)
                acc[i][j] = MFMA_BF16(af[i], bfr[j], acc[i][j]);
    }
#pragma unroll
    for (int i = 0; i < 2; ++i)
#pragma unroll
        for (int j = 0; j < 2; ++j) {
            size_t rr = bm + wm + i * 16 + g * 4;
            size_t cc = bn + wn + j * 16 + lr;
#pragma unroll
            for (int r = 0; r < 4; ++r)
                C[(rr + r) * (size_t)N + cc] = f2bf(acc[i][j][r]);
        }
}

// ---------------- GEMM core 256x128: 4 waves, each 128x64 (acc[8][4]), BK=64 -----------------
// LDS: As = 2 kk-halves x 256x32 (16384 el, 32KB); Bs = 2 x 128x32 (8192 el, 16KB).
// acc left in registers; caller handles epilogue.
static __device__ __forceinline__ void gemm_core256(
    const unsigned short* __restrict__ A,
    const unsigned short* __restrict__ Bt,
    int K, int bx, int by,
    unsigned short* As, unsigned short* Bs,
    f32x4 (&acc)[8][4])
{
    const int tid = threadIdx.x;
    const int wave = tid >> 6, lane = tid & 63;
    const int g = lane >> 4, lr = lane & 15;
    const int wm = (wave >> 1) * 128, wn = (wave & 1) * 64;
    const size_t bm = (size_t)bx * 256, bn = (size_t)by * 128;

    const int srow = tid >> 2, skc = (tid & 3) * 8;   // 64 rows x 32 el per GLL16 round
    const unsigned short* Ap = A + (bm + srow) * (size_t)K + skc;
    const unsigned short* Bp = Bt + (bn + srow) * (size_t)K + skc;

    for (int k0 = 0; k0 < K; k0 += 64) {
        __syncthreads();
#pragma unroll
        for (int kk = 0; kk < 2; ++kk) {
#pragma unroll
            for (int r = 0; r < 4; ++r)
                GLL16(Ap + (size_t)(r * 64) * K + k0 + kk * 32,
                      As + kk * 8192 + r * 2048 + tid * 8);
#pragma unroll
            for (int r = 0; r < 2; ++r)
                GLL16(Bp + (size_t)(r * 64) * K + k0 + kk * 32,
                      Bs + kk * 4096 + r * 2048 + tid * 8);
        }
        __syncthreads();
#pragma unroll
        for (int kk = 0; kk < 2; ++kk) {
            bf16x8 bfr[4];
#pragma unroll
            for (int t = 0; t < 4; ++t)
                bfr[t] = *(const bf16x8*)&Bs[kk * 4096 + (wn + t * 16 + lr) * 32 + g * 8];
#pragma unroll
            for (int rt = 0; rt < 8; ++rt) {
                bf16x8 af = *(const bf16x8*)&As[kk * 8192 + (wm + rt * 16 + lr) * 32 + g * 8];
#pragma unroll
                for (int ct = 0; ct < 4; ++ct)
                    acc[rt][ct] = MFMA_BF16(af, bfr[ct], acc[rt][ct]);
            }
        }
    }
}

// batched q/k/v projections (v = k_in * Wkv); q output pre-scaled for attention exp2
__global__ __launch_bounds__(256) void proj3_kernel(
    const unsigned short* __restrict__ q_in, const unsigned short* __restrict__ k_in,
    const unsigned short* __restrict__ wqt, const unsigned short* __restrict__ wkt,
    const unsigned short* __restrict__ wkvt,
    unsigned short* __restrict__ qb, unsigned short* __restrict__ kb,
    unsigned short* __restrict__ vb)
{
    __shared__ unsigned short As[2 * 256 * 32];
    __shared__ unsigned short Bs[2 * 128 * 32];
    const unsigned short *A, *Bt; unsigned short* C; int mode = 0;
    switch (blockIdx.z) {
        case 0:  A = q_in; Bt = wqt;  C = qb; mode = 2; break;
        case 1:  A = k_in; Bt = wkt;  C = kb; break;
        default: A = k_in; Bt = wkvt; C = vb; break;
    }
    f32x4 acc[8][4] = {};
    gemm_core256(A, Bt, 512, blockIdx.x, blockIdx.y, As, Bs, acc);

    const int tid = threadIdx.x;
    const int wave = tid >> 6, lane = tid & 63;
    const int g = lane >> 4, lr = lane & 15;
    const int wm = (wave >> 1) * 128, wn = (wave & 1) * 64;
    const size_t bm = (size_t)blockIdx.x * 256, bn = (size_t)blockIdx.y * 128;
#pragma unroll
    for (int rt = 0; rt < 8; ++rt)
#pragma unroll
        for (int ct = 0; ct < 4; ++ct) {
            size_t row = bm + wm + rt * 16 + g * 4;
            size_t col = bn + wn + ct * 16 + lr;
#pragma unroll
            for (int r = 0; r < 4; ++r) {
                float x = acc[rt][ct][r];
                if (mode == 2) x *= QSCALE;
                C[(row + r) * (size_t)512 + col] = f2bf(x);
            }
        }
}

// ---------------- ffn1 with fused relu + column-mean: hmean[b][f] += sum_t relu(...) ---------
// grid (32, 16): 512 blocks = exactly one full-device round at 2 blocks/CU.
__global__ __launch_bounds__(256) void ffn1_mean(
    const unsigned short* __restrict__ A,    // result [8192][512]
    const unsigned short* __restrict__ Bt,   // fw1t   [2048][512]
    float* __restrict__ hmean)               // [8][2048]
{
    __shared__ unsigned short As[2 * 256 * 32];
    __shared__ unsigned short Bs[2 * 128 * 32];
    f32x4 acc[8][4] = {};
    gemm_core256(A, Bt, 512, blockIdx.x, blockIdx.y, As, Bs, acc);

    const int tid = threadIdx.x;
    const int wave = tid >> 6, lane = tid & 63;
    const int g = lane >> 4, lr = lane & 15;
    const int wn = (wave & 1) * 64;
    const size_t bn = (size_t)blockIdx.y * 128;
    const int b = blockIdx.x >> 2;            // 256-row tiles: 4 tiles per batch row-block
#pragma unroll
    for (int ct = 0; ct < 4; ++ct) {
        float s = 0.f;
#pragma unroll
        for (int rt = 0; rt < 8; ++rt)
#pragma unroll
            for (int r = 0; r < 4; ++r) s += fmaxf(acc[rt][ct][r], 0.f);
        s += __shfl_xor(s, 16, 64);
        s += __shfl_xor(s, 32, 64);
        if (g == 0)
            atomicAdd(hmean + b * 2048 + bn + wn + ct * 16 + lr, s);
    }
}

// ---------------- ffn2 wide: out[b][d] += (1/1024) * sum_f hmean[b][f] * fw2t[d][f] ----------
__global__ __launch_bounds__(256) void ffn2_small(
    const float* __restrict__ hmean, const unsigned short* __restrict__ fw2t,
    float* __restrict__ out)
{
    __shared__ float red[256];
    const int b = blockIdx.x;
    const int d = blockIdx.y * 64 + (threadIdx.x & 63);
    const int fs = (threadIdx.x >> 6) * 512;
    const float* hm = hmean + b * 2048 + fs;
    const unsigned short* wr = fw2t + (size_t)d * 2048 + fs;
    float acc = 0.f;
    for (int f = 0; f < 512; f += 8) {
        u16x8 w = *(const u16x8*)(wr + f);
        f32x4 h0 = *(const f32x4*)(hm + f);
        f32x4 h1 = *(const f32x4*)(hm + f + 4);
        acc += h0[0] * bf2f(w[0]) + h0[1] * bf2f(w[1]) + h0[2] * bf2f(w[2]) + h0[3] * bf2f(w[3])
             + h1[0] * bf2f(w[4]) + h1[1] * bf2f(w[5]) + h1[2] * bf2f(w[6]) + h1[3] * bf2f(w[7]);
    }
    red[threadIdx.x] = acc;
    __syncthreads();
    if (threadIdx.x < 64) {
        float s = red[threadIdx.x] + red[threadIdx.x + 64] +
                  red[threadIdx.x + 128] + red[threadIdx.x + 192];
        out[b * 512 + d] += s * (1.0f / 1024.0f);
    }
}

// ---------------- flash attention: K/V LDS dbuf, 1 barrier/tile, XCD grid, fused mean --------
// grid (64-bh, 8-qtile): x = bh fastest -> all q-tiles of one (b,h) land on XCD x%8 (L2 reuse).
__global__ __launch_bounds__(512, 2) void attn_kernel(
    const unsigned short* __restrict__ Q,     // pre-scaled by QSCALE
    const unsigned short* __restrict__ Kp,
    const unsigned short* __restrict__ V,
    const float* __restrict__ queries,
    const float* __restrict__ pos,
    const float* __restrict__ kmask,
    const float* __restrict__ qmask,
    unsigned short* __restrict__ Res,
    float* __restrict__ out)
{
    __shared__ unsigned short Ks[2][64 * 72];  // [buf][key][d]
    __shared__ unsigned short Vts[2][64 * 72]; // [buf][d][key]
    __shared__ unsigned short Ps[8][16 * 72];  // per-wave P^T as [q][key]
    __shared__ float kbias[1024];              // additive key-mask bias; reused as red scratch
    const int tid = threadIdx.x, wave = tid >> 6, lane = tid & 63;
    const int g = lane >> 4, lr = lane & 15;
    const int b = blockIdx.x >> 3, h = blockIdx.x & 7;
    const int qg = blockIdx.y * 128 + wave * 16 + lr;

    for (int i = tid; i < 1024; i += 512)
        kbias[i] = (kmask[b * 1024 + i] == 1.0f) ? 0.f : NEGBIG;

    bf16x8 aq0, aq1;
    {
        const unsigned short* qp = Q + ((size_t)(b * 1024 + qg)) * 512 + h * 64 + g * 8;
        aq0 = *(const bf16x8*)qp;
        aq1 = *(const bf16x8*)(qp + 32);
    }
    const float qm = qmask[b * 1024 + qg];

    float m_run = -3.0e38f, l_run = 0.f;
    f32x4 o[4] = {};                           // O^T: d = dt*16+4g+r, q = lr

    const unsigned short* kbase = Kp + ((size_t)(b * 1024)) * 512 + h * 64;
    const unsigned short* vbase = V + ((size_t)(b * 1024)) * 512 + h * 64;

    const int half = tid >> 8;                        // 0: V stager, 1: K stager
    const int skey = (tid & 255) >> 2, sd = (tid & 3) * 16;      // K map
    const int vk0 = (tid & 15) * 4, vd0 = ((tid >> 4) & 15) * 4; // V map (key-major lanes)

    u16x8 kr0, kr1; u16x4 vr[4];
    if (half) {
        const unsigned short* kp = kbase + (size_t)skey * 512 + sd;
        kr0 = *(const u16x8*)kp; kr1 = *(const u16x8*)(kp + 8);
    } else {
        const unsigned short* vp = vbase + (size_t)vk0 * 512 + vd0;
#pragma unroll
        for (int j = 0; j < 4; ++j) vr[j] = *(const u16x4*)(vp + (size_t)j * 512);
    }
    if (half) {
        *(u16x8*)&Ks[0][skey * 72 + sd] = kr0;
        *(u16x8*)&Ks[0][skey * 72 + sd + 8] = kr1;
    } else {
#pragma unroll
        for (int i = 0; i < 4; ++i) {
            u16x4 w = { vr[0][i], vr[1][i], vr[2][i], vr[3][i] };
            *(u16x4*)&Vts[0][(vd0 + i) * 72 + vk0] = w;
        }
    }
    if (half) {
        const unsigned short* kp = kbase + (size_t)(64 + skey) * 512 + sd;
        kr0 = *(const u16x8*)kp; kr1 = *(const u16x8*)(kp + 8);
    } else {
        const unsigned short* vp = vbase + (size_t)(64 + vk0) * 512 + vd0;
#pragma unroll
        for (int j = 0; j < 4; ++j) vr[j] = *(const u16x4*)(vp + (size_t)j * 512);
    }
    __syncthreads();

    for (int it = 0; it < 16; ++it) {
        const int j0 = it * 64;
        const unsigned short* Kc = Ks[it & 1];
        const unsigned short* Vc = Vts[it & 1];

        f32x4 s[4];
#pragma unroll
        for (int ct = 0; ct < 4; ++ct) {
            bf16x8 ka = *(const bf16x8*)&Kc[(ct * 16 + lr) * 72 + g * 8];
            bf16x8 kc = *(const bf16x8*)&Kc[(ct * 16 + lr) * 72 + 32 + g * 8];
            f32x4 z = {};
            z = MFMA_BF16(ka, aq0, z);
            s[ct] = MFMA_BF16(kc, aq1, z);
        }

#pragma unroll
        for (int ct = 0; ct < 4; ++ct)
            s[ct] += *(const f32x4*)&kbias[j0 + ct * 16 + g * 4];
        if (((qg ^ j0) & ~63) == 0) {
#pragma unroll
            for (int ct = 0; ct < 4; ++ct) {
                unsigned diff = (unsigned)(qg - (j0 + ct * 16 + g * 4));
                if (diff < 4u) s[ct][diff] = NEGBIG;
            }
        }
        float rmax = -3.0e38f;
#pragma unroll
        for (int ct = 0; ct < 4; ++ct)
#pragma unroll
            for (int r = 0; r < 4; ++r) rmax = fmaxf(rmax, s[ct][r]);
        rmax = fmaxf(rmax, __shfl_xor(rmax, 16, 64));
        rmax = fmaxf(rmax, __shfl_xor(rmax, 32, 64));

        float mn = fmaxf(m_run, rmax);
        float alpha = EXP2(m_run - mn);
        m_run = mn;
        float psum = 0.f;
#pragma unroll
        for (int ct = 0; ct < 4; ++ct) {
            f32x4 p;
#pragma unroll
            for (int r = 0; r < 4; ++r) { p[r] = EXP2(s[ct][r] - mn); psum += p[r]; }
            bf16x4 pk = { (__bf16)p[0], (__bf16)p[1], (__bf16)p[2], (__bf16)p[3] };
            *(bf16x4*)&Ps[wave][lr * 72 + ct * 16 + g * 4] = pk;
        }
        psum += __shfl_xor(psum, 16, 64);
        psum += __shfl_xor(psum, 32, 64);
        l_run = l_run * alpha + psum;
#pragma unroll
        for (int dt = 0; dt < 4; ++dt) o[dt] *= alpha;

        bf16x8 p0 = *(const bf16x8*)&Ps[wave][lr * 72 + g * 8];
        bf16x8 p1 = *(const bf16x8*)&Ps[wave][lr * 72 + 32 + g * 8];
#pragma unroll
        for (int dt = 0; dt < 4; ++dt) {
            bf16x8 va = *(const bf16x8*)&Vc[(dt * 16 + lr) * 72 + g * 8];
            bf16x8 vc = *(const bf16x8*)&Vc[(dt * 16 + lr) * 72 + 32 + g * 8];
            o[dt] = MFMA_BF16(va, p0, o[dt]);
            o[dt] = MFMA_BF16(vc, p1, o[dt]);
        }

        if (it + 1 < 16) {
            unsigned short* Kn = Ks[(it + 1) & 1];
            unsigned short* Vn = Vts[(it + 1) & 1];
            if (half) {
                *(u16x8*)&Kn[skey * 72 + sd] = kr0;
                *(u16x8*)&Kn[skey * 72 + sd + 8] = kr1;
            } else {
#pragma unroll
                for (int i = 0; i < 4; ++i) {
                    u16x4 w = { vr[0][i], vr[1][i], vr[2][i], vr[3][i] };
                    *(u16x4*)&Vn[(vd0 + i) * 72 + vk0] = w;
                }
            }
        }
        if (it + 2 < 16) {
            const int jn = (it + 2) * 64;
            if (half) {
                const unsigned short* kp = kbase + (size_t)(jn + skey) * 512 + sd;
                kr0 = *(const u16x8*)kp; kr1 = *(const u16x8*)(kp + 8);
            } else {
                const unsigned short* vp = vbase + (size_t)(jn + vk0) * 512 + vd0;
#pragma unroll
                for (int j = 0; j < 4; ++j) vr[j] = *(const u16x4*)(vp + (size_t)j * 512);
            }
        }
        __syncthreads();
    }

    const float inv_l = 1.0f / l_run;
    const float S = 22.627416997969522f;
    float vals[4][4];
#pragma unroll
    for (int dt = 0; dt < 4; ++dt) {
        size_t col = (size_t)h * 64 + dt * 16 + g * 4;
        size_t idx = ((size_t)(b * 1024 + qg)) * 512 + col;
        f32x4 qv = *(const f32x4*)&queries[idx];
        f32x4 pv = *(const f32x4*)&pos[(size_t)qg * 512 + col];
        u16x4 wr;
#pragma unroll
        for (int r = 0; r < 4; ++r) {
            float v = o[dt][r] * inv_l * qm + qv[r] + pv[r] * S;
            vals[dt][r] = v;
            wr[r] = f2bf(v);
        }
        *(u16x4*)&Res[idx] = wr;
    }

    float* red = kbias;
#pragma unroll
    for (int dt = 0; dt < 4; ++dt)
#pragma unroll
        for (int r = 0; r < 4; ++r) {
            float x = vals[dt][r];
            x += __shfl_xor(x, 1, 64);
            x += __shfl_xor(x, 2, 64);
            x += __shfl_xor(x, 4, 64);
            x += __shfl_xor(x, 8, 64);
            if (lr == 0) red[wave * 64 + dt * 16 + g * 4 + r] = x;
        }
    __syncthreads();
    if (tid < 64) {
        float s = 0.f;
#pragma unroll
        for (int w = 0; w < 8; ++w) s += red[w * 64 + tid];
        atomicAdd(out + b * 512 + h * 64 + tid, s * (1.0f / 1024.0f));
    }
}

extern "C" void kernel_launch(void* const* d_in, const int* in_sizes, int n_in,
                              void* d_out, int out_size, void* d_ws, size_t ws_size,
                              hipStream_t stream)
{
    (void)in_sizes; (void)n_in; (void)out_size; (void)ws_size;
    const float* queries     = (const float*)d_in[0];
    const float* keys        = (const float*)d_in[1];
    const float* query_masks = (const float*)d_in[2];
    const float* key_masks   = (const float*)d_in[3];
    const float* pos_table   = (const float*)d_in[4];
    const float* W_Query     = (const float*)d_in[5];
    const float* W_key       = (const float*)d_in[6];
    const float* W_Value     = (const float*)d_in[7];
    const float* fw1         = (const float*)d_in[8];
    const float* fw2         = (const float*)d_in[9];
    float* out = (float*)d_out;

    unsigned short* ws = (unsigned short*)d_ws;
    const size_t NE = (size_t)8 * 1024 * 512;
    unsigned short* q_in   = ws;               // -> result after attn
    unsigned short* k_in   = ws + NE;
    unsigned short* qb     = ws + 2 * NE;
    unsigned short* kb     = ws + 3 * NE;
    unsigned short* vb     = ws + 4 * NE;
    unsigned short* result = q_in;
    unsigned short* wqt    = ws + 6 * NE;
    unsigned short* wkt    = wqt + 512 * 512;
    unsigned short* wvt    = wkt + 512 * 512;
    unsigned short* fw1t   = wvt + 512 * 512;     // 2048 x 512
    unsigned short* fw2t   = fw1t + 2048 * 512;   // 512 x 2048
    unsigned short* wkp    = fw2t + 2048 * 512;   // bf16(W_key), plain
    unsigned short* wkvt   = wkp + 512 * 512;     // (Wk*Wv)^T
    float*          hmean  = (float*)(wkvt + 512 * 512);  // 8 x 2048 fp32

    hipMemsetAsync(d_out, 0, 8 * 512 * sizeof(float), stream);
    hipMemsetAsync(hmean, 0, 8 * 2048 * sizeof(float), stream);
    prep_kernel<<<4096, 256, 0, stream>>>(queries, keys, pos_table, q_in, k_in);
    wconv_kernel<<<2816, 256, 0, stream>>>(W_Query, W_key, W_Value, fw1, fw2,
                                           wqt, wkt, wvt, fw1t, fw2t, wkp);
    gemm64<<<dim3(8, 8), 256, 0, stream>>>(wvt, wkp, wkvt, 512, 512);
    proj3_kernel<<<dim3(32, 4, 3), 256, 0, stream>>>(q_in, k_in, wqt, wkt, wkvt, qb, kb, vb);
    attn_kernel<<<dim3(64, 8), 512, 0, stream>>>(qb, kb, vb, queries, pos_table,
                                                 key_masks, query_masks, result, out);
    ffn1_mean<<<dim3(32, 16), 256, 0, stream>>>(result, fw1t, hmean);
    ffn2_small<<<dim3(8, 8), 256, 0, stream>>>(hmean, fw2t, out);
}

// Round 10
// 207.066 us; speedup vs baseline: 1.1555x; 1.1555x over previous
//
#include <hip/hip_runtime.h>

// B=8, T=1024, D=512, H=8, dh=64.
// Pipeline: prep(+zero out/hmean) -> wconv -> Wkv^T (gemm64) -> batched q/k/v proj (r8 core) ->
// flash attention (32q/wave = TWO independent 16-q chains, K/V dbuf, 1 barrier/tile, XCD grid,
// fused result-mean) -> ffn1 (r8 core) fused relu+column-mean -> ffn2 wide.
// LESSONS: r7/r9 — never trade resident waves for per-wave work unless it's independent work;
// attn 2-chain structure is the correct form. GEMM core: 128x128 BK=64 is the proven optimum.

typedef __bf16 bf16x8 __attribute__((ext_vector_type(8)));
typedef __bf16 bf16x4 __attribute__((ext_vector_type(4)));
typedef float f32x4 __attribute__((ext_vector_type(4)));
typedef unsigned short u16x8 __attribute__((ext_vector_type(8)));
typedef unsigned short u16x4 __attribute__((ext_vector_type(4)));

#define MFMA_BF16(a, b, c) __builtin_amdgcn_mfma_f32_16x16x32_bf16((a), (b), (c), 0, 0, 0)
#define NEGBIG (-4294967295.0f)
#define QSCALE 0.18033688011112042f   // 0.125 * log2(e)
#define EXP2(x) __builtin_amdgcn_exp2f(x)

#define GLL16(g, l)                                                                 \
    __builtin_amdgcn_global_load_lds((__attribute__((address_space(1))) void*)(g),  \
                                     (__attribute__((address_space(3))) void*)(l),  \
                                     16, 0, 0)

static __device__ __forceinline__ unsigned short f2bf(float f) {
    __bf16 h = (__bf16)f;
    return __builtin_bit_cast(unsigned short, h);
}
static __device__ __forceinline__ float bf2f(unsigned short h) {
    return __builtin_bit_cast(float, ((unsigned int)h) << 16);
}

// ---------------- prep: q_in/k_in = inputs + pos*sqrt(512); blocks 0-4 also zero out/hmean ---
__global__ __launch_bounds__(256) void prep_kernel(
    const float* __restrict__ q, const float* __restrict__ k,
    const float* __restrict__ pos,
    unsigned short* __restrict__ qo, unsigned short* __restrict__ ko,
    float* __restrict__ out, float* __restrict__ hmean)
{
    if (blockIdx.x < 5) {                      // zero out (4096 f) + hmean (16384 f)
        float* dst = (blockIdx.x == 0) ? out : hmean + (blockIdx.x - 1) * 4096;
        float4 z = {0.f, 0.f, 0.f, 0.f};
#pragma unroll
        for (int j = 0; j < 4; ++j)
            *(float4*)(dst + threadIdx.x * 16 + j * 4) = z;
    }
    size_t i = ((size_t)blockIdx.x * 256 + threadIdx.x) * 4;
    size_t td = i & (size_t)(1024 * 512 - 1);
    float4 qv = *(const float4*)(q + i);
    float4 kv = *(const float4*)(k + i);
    float4 pv = *(const float4*)(pos + td);
    const float S = 22.627416997969522f;
    u16x4 qr, kr;
    qr[0] = f2bf(qv.x + pv.x * S); qr[1] = f2bf(qv.y + pv.y * S);
    qr[2] = f2bf(qv.z + pv.z * S); qr[3] = f2bf(qv.w + pv.w * S);
    kr[0] = f2bf(kv.x + pv.x * S); kr[1] = f2bf(kv.y + pv.y * S);
    kr[2] = f2bf(kv.z + pv.z * S); kr[3] = f2bf(kv.w + pv.w * S);
    *(u16x4*)(qo + i) = qr;
    *(u16x4*)(ko + i) = kr;
}

// ---------------- weight transpose + cast, exact 1D grid (2816 blocks) -----------------------
__global__ __launch_bounds__(256) void wconv_kernel(
    const float* __restrict__ w0, const float* __restrict__ w1, const float* __restrict__ w2,
    const float* __restrict__ w3, const float* __restrict__ w4,
    unsigned short* __restrict__ o0, unsigned short* __restrict__ o1, unsigned short* __restrict__ o2,
    unsigned short* __restrict__ o3, unsigned short* __restrict__ o4,
    unsigned short* __restrict__ wkp)
{
    int id = blockIdx.x;
    const float* in; unsigned short* out; int K, N, kt, nt; bool dup = false;
    if (id < 768) {
        int m = id >> 8; id &= 255;
        in  = (m == 0) ? w0 : ((m == 1) ? w1 : w2);
        out = (m == 0) ? o0 : ((m == 1) ? o1 : o2);
        dup = (m == 1);
        K = 512; N = 512; kt = id >> 4; nt = id & 15;
    } else if (id < 1792) {
        id -= 768; in = w3; out = o3; K = 512; N = 2048; kt = id >> 6; nt = id & 63;
    } else {
        id -= 1792; in = w4; out = o4; K = 2048; N = 512; kt = id >> 4; nt = id & 15;
    }
    int k0 = kt * 32, n0 = nt * 32;
    __shared__ float tile[32][33];
    int tx = threadIdx.x & 31, ty = threadIdx.x >> 5;
#pragma unroll
    for (int i = 0; i < 32; i += 8) {
        float v = in[(size_t)(k0 + ty + i) * N + n0 + tx];
        tile[ty + i][tx] = v;
        if (dup) wkp[(size_t)(k0 + ty + i) * 512 + n0 + tx] = f2bf(v);
    }
    __syncthreads();
#pragma unroll
    for (int i = 0; i < 32; i += 8)
        out[(size_t)(n0 + ty + i) * K + k0 + tx] = f2bf(tile[tx][ty + i]);
}

// ---------------- small GEMM, 64x64 tiles (Wkv^T = Wv^T * Wk): grid (8,8) -------------------
__global__ __launch_bounds__(256) void gemm64(
    const unsigned short* __restrict__ A, const unsigned short* __restrict__ Bt,
    unsigned short* __restrict__ C, int N, int K)
{
    __shared__ unsigned short As[64 * 32];
    __shared__ unsigned short Bs[64 * 32];
    const int tid = threadIdx.x;
    const int wave = tid >> 6, lane = tid & 63;
    const int g = lane >> 4, lr = lane & 15;
    const int wm = (wave >> 1) * 32, wn = (wave & 1) * 32;
    const size_t bm = (size_t)blockIdx.x * 64, bn = (size_t)blockIdx.y * 64;
    const int row = tid >> 2, kc = (tid & 3) * 8;
    const unsigned short* Ap = A + (bm + row) * (size_t)K + kc;
    const unsigned short* Bp = Bt + (bn + row) * (size_t)K + kc;
    unsigned short* AsW = As + tid * 8;
    unsigned short* BsW = Bs + tid * 8;

    f32x4 acc[2][2] = {};
    for (int k0 = 0; k0 < K; k0 += 32) {
        __syncthreads();
        GLL16(Ap + k0, AsW);
        GLL16(Bp + k0, BsW);
        __syncthreads();
        bf16x8 af[2], bfr[2];
#pragma unroll
        for (int t = 0; t < 2; ++t) {
            af[t]  = *(const bf16x8*)&As[(wm + t * 16 + lr) * 32 + g * 8];
            bfr[t] = *(const bf16x8*)&Bs[(wn + t * 16 + lr) * 32 + g * 8];
        }
#pragma unroll
        for (int i = 0; i < 2; ++i)
#pragma unroll
            for (int j = 0; j < 2; ++j)
                acc[i][j] = MFMA_BF16(af[i], bfr[j], acc[i][j]);
    }
#pragma unroll
    for (int i = 0; i < 2; ++i)
#pragma unroll
        for (int j = 0; j < 2; ++j) {
            size_t rr = bm + wm + i * 16 + g * 4;
            size_t cc = bn + wn + j * 16 + lr;
#pragma unroll
            for (int r = 0; r < 4; ++r)
                C[(rr + r) * (size_t)N + cc] = f2bf(acc[i][j][r]);
        }
}

// ---------------- GEMM core (r8): 128x128 tile, BK=64 (two concatenated 128x32 halves) -------
static __device__ __forceinline__ void gemm_core(
    const unsigned short* __restrict__ A,
    const unsigned short* __restrict__ Bt,
    unsigned short* __restrict__ C,
    int N, int K, int mode,
    unsigned short* As, unsigned short* Bs, int bx, int by)
{
    const int tid = threadIdx.x;
    const int wave = tid >> 6, lane = tid & 63;
    const int g = lane >> 4, lr = lane & 15;
    const int wm = (wave >> 1) * 64, wn = (wave & 1) * 64;
    const size_t bm = (size_t)bx * 128, bn = (size_t)by * 128;

    const int srow = tid >> 2, skc = (tid & 3) * 8;
    const unsigned short* Ap = A + (bm + srow) * (size_t)K + skc;
    const unsigned short* Bp = Bt + (bn + srow) * (size_t)K + skc;

    f32x4 acc[4][4] = {};
    for (int k0 = 0; k0 < K; k0 += 64) {
        __syncthreads();
        GLL16(Ap + k0,                        As + tid * 8);
        GLL16(Ap + (size_t)64 * K + k0,       As + 2048 + tid * 8);
        GLL16(Ap + k0 + 32,                   As + 4096 + tid * 8);
        GLL16(Ap + (size_t)64 * K + k0 + 32,  As + 6144 + tid * 8);
        GLL16(Bp + k0,                        Bs + tid * 8);
        GLL16(Bp + (size_t)64 * K + k0,       Bs + 2048 + tid * 8);
        GLL16(Bp + k0 + 32,                   Bs + 4096 + tid * 8);
        GLL16(Bp + (size_t)64 * K + k0 + 32,  Bs + 6144 + tid * 8);
        __syncthreads();
#pragma unroll
        for (int kk = 0; kk < 2; ++kk) {
            bf16x8 af[4], bfr[4];
#pragma unroll
            for (int t = 0; t < 4; ++t) {
                af[t]  = *(const bf16x8*)&As[kk * 4096 + (wm + t * 16 + lr) * 32 + g * 8];
                bfr[t] = *(const bf16x8*)&Bs[kk * 4096 + (wn + t * 16 + lr) * 32 + g * 8];
            }
#pragma unroll
            for (int rt = 0; rt < 4; ++rt)
#pragma unroll
                for (int ct = 0; ct < 4; ++ct)
                    acc[rt][ct] = MFMA_BF16(af[rt], bfr[ct], acc[rt][ct]);
        }
    }

#pragma unroll
    for (int rt = 0; rt < 4; ++rt)
#pragma unroll
        for (int ct = 0; ct < 4; ++ct) {
            size_t row = bm + wm + rt * 16 + g * 4;
            size_t col = bn + wn + ct * 16 + lr;
#pragma unroll
            for (int r = 0; r < 4; ++r) {
                float x = acc[rt][ct][r];
                if (mode == 2) x *= QSCALE;
                C[(row + r) * (size_t)N + col] = f2bf(x);
            }
        }
}

// batched q/k/v projections (v = k_in * Wkv); q output pre-scaled for attention exp2
__global__ __launch_bounds__(256, 2) void proj3_kernel(
    const unsigned short* __restrict__ q_in, const unsigned short* __restrict__ k_in,
    const unsigned short* __restrict__ wqt, const unsigned short* __restrict__ wkt,
    const unsigned short* __restrict__ wkvt,
    unsigned short* __restrict__ qb, unsigned short* __restrict__ kb,
    unsigned short* __restrict__ vb)
{
    __shared__ unsigned short As[128 * 64];
    __shared__ unsigned short Bs[128 * 64];
    const unsigned short *A, *Bt; unsigned short* C; int mode = 0;
    switch (blockIdx.z) {
        case 0:  A = q_in; Bt = wqt;  C = qb; mode = 2; break;
        case 1:  A = k_in; Bt = wkt;  C = kb; break;
        default: A = k_in; Bt = wkvt; C = vb; break;
    }
    gemm_core(A, Bt, C, 512, 512, mode, As, Bs, blockIdx.x, blockIdx.y);
}

// ---------------- ffn1 with fused relu + column-mean: hmean[b][f] += sum_t relu(...) ---------
__global__ __launch_bounds__(256, 2) void ffn1_mean(
    const unsigned short* __restrict__ A,    // result [8192][512]
    const unsigned short* __restrict__ Bt,   // fw1t   [2048][512]
    float* __restrict__ hmean)               // [8][2048]
{
    __shared__ unsigned short As[128 * 64];
    __shared__ unsigned short Bs[128 * 64];
    const int tid = threadIdx.x;
    const int wave = tid >> 6, lane = tid & 63;
    const int g = lane >> 4, lr = lane & 15;
    const int wm = (wave >> 1) * 64, wn = (wave & 1) * 64;
    const size_t bm = (size_t)blockIdx.x * 128, bn = (size_t)blockIdx.y * 128;

    const int srow = tid >> 2, skc = (tid & 3) * 8;
    const unsigned short* Ap = A + (bm + srow) * (size_t)512 + skc;
    const unsigned short* Bp = Bt + (bn + srow) * (size_t)512 + skc;

    f32x4 acc[4][4] = {};
    for (int k0 = 0; k0 < 512; k0 += 64) {
        __syncthreads();
        GLL16(Ap + k0,                         As + tid * 8);
        GLL16(Ap + (size_t)64 * 512 + k0,      As + 2048 + tid * 8);
        GLL16(Ap + k0 + 32,                    As + 4096 + tid * 8);
        GLL16(Ap + (size_t)64 * 512 + k0 + 32, As + 6144 + tid * 8);
        GLL16(Bp + k0,                         Bs + tid * 8);
        GLL16(Bp + (size_t)64 * 512 + k0,      Bs + 2048 + tid * 8);
        GLL16(Bp + k0 + 32,                    Bs + 4096 + tid * 8);
        GLL16(Bp + (size_t)64 * 512 + k0 + 32, Bs + 6144 + tid * 8);
        __syncthreads();
#pragma unroll
        for (int kk = 0; kk < 2; ++kk) {
            bf16x8 af[4], bfr[4];
#pragma unroll
            for (int t = 0; t < 4; ++t) {
                af[t]  = *(const bf16x8*)&As[kk * 4096 + (wm + t * 16 + lr) * 32 + g * 8];
                bfr[t] = *(const bf16x8*)&Bs[kk * 4096 + (wn + t * 16 + lr) * 32 + g * 8];
            }
#pragma unroll
            for (int rt = 0; rt < 4; ++rt)
#pragma unroll
                for (int ct = 0; ct < 4; ++ct)
                    acc[rt][ct] = MFMA_BF16(af[rt], bfr[ct], acc[rt][ct]);
        }
    }

    const int b = blockIdx.x >> 3;
#pragma unroll
    for (int ct = 0; ct < 4; ++ct) {
        float s = 0.f;
#pragma unroll
        for (int rt = 0; rt < 4; ++rt)
#pragma unroll
            for (int r = 0; r < 4; ++r) s += fmaxf(acc[rt][ct][r], 0.f);
        s += __shfl_xor(s, 16, 64);
        s += __shfl_xor(s, 32, 64);
        if (g == 0)
            atomicAdd(hmean + b * 2048 + bn + wn + ct * 16 + lr, s);
    }
}

// ---------------- ffn2 wide: out[b][d] += (1/1024) * sum_f hmean[b][f] * fw2t[d][f] ----------
__global__ __launch_bounds__(256) void ffn2_small(
    const float* __restrict__ hmean, const unsigned short* __restrict__ fw2t,
    float* __restrict__ out)
{
    __shared__ float red[256];
    const int b = blockIdx.x;
    const int d = blockIdx.y * 64 + (threadIdx.x & 63);
    const int fs = (threadIdx.x >> 6) * 512;
    const float* hm = hmean + b * 2048 + fs;
    const unsigned short* wr = fw2t + (size_t)d * 2048 + fs;
    float acc = 0.f;
    for (int f = 0; f < 512; f += 8) {
        u16x8 w = *(const u16x8*)(wr + f);
        f32x4 h0 = *(const f32x4*)(hm + f);
        f32x4 h1 = *(const f32x4*)(hm + f + 4);
        acc += h0[0] * bf2f(w[0]) + h0[1] * bf2f(w[1]) + h0[2] * bf2f(w[2]) + h0[3] * bf2f(w[3])
             + h1[0] * bf2f(w[4]) + h1[1] * bf2f(w[5]) + h1[2] * bf2f(w[6]) + h1[3] * bf2f(w[7]);
    }
    red[threadIdx.x] = acc;
    __syncthreads();
    if (threadIdx.x < 64) {
        float s = red[threadIdx.x] + red[threadIdx.x + 64] +
                  red[threadIdx.x + 128] + red[threadIdx.x + 192];
        out[b * 512 + d] += s * (1.0f / 1024.0f);
    }
}

// ---------------- flash attention: 32 q/wave = 2 independent 16-q chains ---------------------
// grid (64-bh, 4-qtile): x = bh fastest -> (b,h) panel stays on XCD x%8. 256 q/block, 8 waves.
// K/V LDS double-buffer, ONE barrier per 64-key tile; per-wave TWO Ps regions (78KB LDS,
// 1 block/CU by design — per-wave ILP doubled via independent chains).
__global__ __launch_bounds__(512) void attn_kernel(
    const unsigned short* __restrict__ Q,     // pre-scaled by QSCALE
    const unsigned short* __restrict__ Kp,
    const unsigned short* __restrict__ V,
    const float* __restrict__ queries,
    const float* __restrict__ pos,
    const float* __restrict__ kmask,
    const float* __restrict__ qmask,
    unsigned short* __restrict__ Res,
    float* __restrict__ out)
{
    __shared__ unsigned short Ks[2][64 * 72];   // [buf][key][d]
    __shared__ unsigned short Vts[2][64 * 72];  // [buf][d][key]
    __shared__ unsigned short Ps[8][2][16 * 72];// per-wave, per-chain P^T as [q][key]
    __shared__ float kbias[1024];               // additive key-mask bias; reused as red scratch
    const int tid = threadIdx.x, wave = tid >> 6, lane = tid & 63;
    const int g = lane >> 4, lr = lane & 15;
    const int b = blockIdx.x >> 3, h = blockIdx.x & 7;
    const int qg0 = blockIdx.y * 256 + wave * 32 + lr;   // chain u: qg0 + u*16

    for (int i = tid; i < 1024; i += 512)
        kbias[i] = (kmask[b * 1024 + i] == 1.0f) ? 0.f : NEGBIG;

    bf16x8 aq[2][2];
    float qm[2], m_run[2], l_run[2];
    f32x4 o[2][4];
#pragma unroll
    for (int u = 0; u < 2; ++u) {
        const unsigned short* qp = Q + ((size_t)(b * 1024 + qg0 + u * 16)) * 512 + h * 64 + g * 8;
        aq[u][0] = *(const bf16x8*)qp;
        aq[u][1] = *(const bf16x8*)(qp + 32);
        qm[u] = qmask[b * 1024 + qg0 + u * 16];
        m_run[u] = -3.0e38f; l_run[u] = 0.f;
#pragma unroll
        for (int dt = 0; dt < 4; ++dt) o[u][dt] = (f32x4){0.f, 0.f, 0.f, 0.f};
    }

    const unsigned short* kbase = Kp + ((size_t)(b * 1024)) * 512 + h * 64;
    const unsigned short* vbase = V + ((size_t)(b * 1024)) * 512 + h * 64;

    const int half = tid >> 8;                        // 0: V stager, 1: K stager
    const int skey = (tid & 255) >> 2, sd = (tid & 3) * 16;      // K map
    const int vk0 = (tid & 15) * 4, vd0 = ((tid >> 4) & 15) * 4; // V map (key-major lanes)

    u16x8 kr0, kr1; u16x4 vr[4];
    if (half) {
        const unsigned short* kp = kbase + (size_t)skey * 512 + sd;
        kr0 = *(const u16x8*)kp; kr1 = *(const u16x8*)(kp + 8);
    } else {
        const unsigned short* vp = vbase + (size_t)vk0 * 512 + vd0;
#pragma unroll
        for (int j = 0; j < 4; ++j) vr[j] = *(const u16x4*)(vp + (size_t)j * 512);
    }
    if (half) {
        *(u16x8*)&Ks[0][skey * 72 + sd] = kr0;
        *(u16x8*)&Ks[0][skey * 72 + sd + 8] = kr1;
    } else {
#pragma unroll
        for (int i = 0; i < 4; ++i) {
            u16x4 w = { vr[0][i], vr[1][i], vr[2][i], vr[3][i] };
            *(u16x4*)&Vts[0][(vd0 + i) * 72 + vk0] = w;
        }
    }
    if (half) {
        const unsigned short* kp = kbase + (size_t)(64 + skey) * 512 + sd;
        kr0 = *(const u16x8*)kp; kr1 = *(const u16x8*)(kp + 8);
    } else {
        const unsigned short* vp = vbase + (size_t)(64 + vk0) * 512 + vd0;
#pragma unroll
        for (int j = 0; j < 4; ++j) vr[j] = *(const u16x4*)(vp + (size_t)j * 512);
    }
    __syncthreads();

    for (int it = 0; it < 16; ++it) {
        const int j0 = it * 64;
        const unsigned short* Kc = Ks[it & 1];
        const unsigned short* Vc = Vts[it & 1];

        // S^T for both chains first (16 independent MFMAs fill the matrix pipe)
        f32x4 s[2][4];
#pragma unroll
        for (int u = 0; u < 2; ++u)
#pragma unroll
            for (int ct = 0; ct < 4; ++ct) {
                bf16x8 ka = *(const bf16x8*)&Kc[(ct * 16 + lr) * 72 + g * 8];
                bf16x8 kc = *(const bf16x8*)&Kc[(ct * 16 + lr) * 72 + 32 + g * 8];
                f32x4 z = {};
                z = MFMA_BF16(ka, aq[u][0], z);
                s[u][ct] = MFMA_BF16(kc, aq[u][1], z);
            }

        // per-chain: bias, diag, softmax, Ps write, PV  (chain u+1's VALU overlaps chain u's PV)
#pragma unroll
        for (int u = 0; u < 2; ++u) {
            const int qgu = qg0 + u * 16;
#pragma unroll
            for (int ct = 0; ct < 4; ++ct)
                s[u][ct] += *(const f32x4*)&kbias[j0 + ct * 16 + g * 4];
            if (((qgu ^ j0) & ~63) == 0) {           // wave-uniform diag blinding
#pragma unroll
                for (int ct = 0; ct < 4; ++ct) {
                    unsigned diff = (unsigned)(qgu - (j0 + ct * 16 + g * 4));
                    if (diff < 4u) s[u][ct][diff] = NEGBIG;
                }
            }
            float rmax = -3.0e38f;
#pragma unroll
            for (int ct = 0; ct < 4; ++ct)
#pragma unroll
                for (int r = 0; r < 4; ++r) rmax = fmaxf(rmax, s[u][ct][r]);
            rmax = fmaxf(rmax, __shfl_xor(rmax, 16, 64));
            rmax = fmaxf(rmax, __shfl_xor(rmax, 32, 64));

            float mn = fmaxf(m_run[u], rmax);
            float alpha = EXP2(m_run[u] - mn);
            m_run[u] = mn;
            float psum = 0.f;
#pragma unroll
            for (int ct = 0; ct < 4; ++ct) {
                f32x4 p;
#pragma unroll
                for (int r = 0; r < 4; ++r) { p[r] = EXP2(s[u][ct][r] - mn); psum += p[r]; }
                bf16x4 pk = { (__bf16)p[0], (__bf16)p[1], (__bf16)p[2], (__bf16)p[3] };
                *(bf16x4*)&Ps[wave][u][lr * 72 + ct * 16 + g * 4] = pk;
            }
            psum += __shfl_xor(psum, 16, 64);
            psum += __shfl_xor(psum, 32, 64);
            l_run[u] = l_run[u] * alpha + psum;
#pragma unroll
            for (int dt = 0; dt < 4; ++dt) o[u][dt] *= alpha;

            bf16x8 p0 = *(const bf16x8*)&Ps[wave][u][lr * 72 + g * 8];
            bf16x8 p1 = *(const bf16x8*)&Ps[wave][u][lr * 72 + 32 + g * 8];
#pragma unroll
            for (int dt = 0; dt < 4; ++dt) {
                bf16x8 va = *(const bf16x8*)&Vc[(dt * 16 + lr) * 72 + g * 8];
                bf16x8 vc = *(const bf16x8*)&Vc[(dt * 16 + lr) * 72 + 32 + g * 8];
                o[u][dt] = MFMA_BF16(va, p0, o[u][dt]);
                o[u][dt] = MFMA_BF16(vc, p1, o[u][dt]);
            }
        }

        // store prefetched tile (it+1) into the other buffer; prefetch tile it+2
        if (it + 1 < 16) {
            unsigned short* Kn = Ks[(it + 1) & 1];
            unsigned short* Vn = Vts[(it + 1) & 1];
            if (half) {
                *(u16x8*)&Kn[skey * 72 + sd] = kr0;
                *(u16x8*)&Kn[skey * 72 + sd + 8] = kr1;
            } else {
#pragma unroll
                for (int i = 0; i < 4; ++i) {
                    u16x4 w = { vr[0][i], vr[1][i], vr[2][i], vr[3][i] };
                    *(u16x4*)&Vn[(vd0 + i) * 72 + vk0] = w;
                }
            }
        }
        if (it + 2 < 16) {
            const int jn = (it + 2) * 64;
            if (half) {
                const unsigned short* kp = kbase + (size_t)(jn + skey) * 512 + sd;
                kr0 = *(const u16x8*)kp; kr1 = *(const u16x8*)(kp + 8);
            } else {
                const unsigned short* vp = vbase + (size_t)(jn + vk0) * 512 + vd0;
#pragma unroll
                for (int j = 0; j < 4; ++j) vr[j] = *(const u16x4*)(vp + (size_t)j * 512);
            }
        }
        __syncthreads();                           // single barrier per key-tile
    }

    // epilogue: normalize, query-mask, residual; store Res; fused mean over q
    const float S = 22.627416997969522f;
    float vals[2][4][4];
#pragma unroll
    for (int u = 0; u < 2; ++u) {
        const float inv_l = 1.0f / l_run[u];
        const int qgu = qg0 + u * 16;
#pragma unroll
        for (int dt = 0; dt < 4; ++dt) {
            size_t col = (size_t)h * 64 + dt * 16 + g * 4;
            size_t idx = ((size_t)(b * 1024 + qgu)) * 512 + col;
            f32x4 qv = *(const f32x4*)&queries[idx];
            f32x4 pv = *(const f32x4*)&pos[(size_t)qgu * 512 + col];
            u16x4 wr;
#pragma unroll
            for (int r = 0; r < 4; ++r) {
                float v = o[u][dt][r] * inv_l * qm[u] + qv[r] + pv[r] * S;
                vals[u][dt][r] = v;
                wr[r] = f2bf(v);
            }
            *(u16x4*)&Res[idx] = wr;
        }
    }

    float* red = kbias;                            // kbias reads done (final barrier above)
#pragma unroll
    for (int dt = 0; dt < 4; ++dt)
#pragma unroll
        for (int r = 0; r < 4; ++r) {
            float x = vals[0][dt][r] + vals[1][dt][r];
            x += __shfl_xor(x, 1, 64);
            x += __shfl_xor(x, 2, 64);
            x += __shfl_xor(x, 4, 64);
            x += __shfl_xor(x, 8, 64);
            if (lr == 0) red[wave * 64 + dt * 16 + g * 4 + r] = x;
        }
    __syncthreads();
    if (tid < 64) {
        float s = 0.f;
#pragma unroll
        for (int w = 0; w < 8; ++w) s += red[w * 64 + tid];
        atomicAdd(out + b * 512 + h * 64 + tid, s * (1.0f / 1024.0f));
    }
}

extern "C" void kernel_launch(void* const* d_in, const int* in_sizes, int n_in,
                              void* d_out, int out_size, void* d_ws, size_t ws_size,
                              hipStream_t stream)
{
    (void)in_sizes; (void)n_in; (void)out_size; (void)ws_size;
    const float* queries     = (const float*)d_in[0];
    const float* keys        = (const float*)d_in[1];
    const float* query_masks = (const float*)d_in[2];
    const float* key_masks   = (const float*)d_in[3];
    const float* pos_table   = (const float*)d_in[4];
    const float* W_Query     = (const float*)d_in[5];
    const float* W_key       = (const float*)d_in[6];
    const float* W_Value     = (const float*)d_in[7];
    const float* fw1         = (const float*)d_in[8];
    const float* fw2         = (const float*)d_in[9];
    float* out = (float*)d_out;

    unsigned short* ws = (unsigned short*)d_ws;
    const size_t NE = (size_t)8 * 1024 * 512;
    unsigned short* q_in   = ws;               // -> result after attn
    unsigned short* k_in   = ws + NE;
    unsigned short* qb     = ws + 2 * NE;
    unsigned short* kb     = ws + 3 * NE;
    unsigned short* vb     = ws + 4 * NE;
    unsigned short* result = q_in;
    unsigned short* wqt    = ws + 6 * NE;
    unsigned short* wkt    = wqt + 512 * 512;
    unsigned short* wvt    = wkt + 512 * 512;
    unsigned short* fw1t   = wvt + 512 * 512;     // 2048 x 512
    unsigned short* fw2t   = fw1t + 2048 * 512;   // 512 x 2048
    unsigned short* wkp    = fw2t + 2048 * 512;   // bf16(W_key), plain
    unsigned short* wkvt   = wkp + 512 * 512;     // (Wk*Wv)^T
    float*          hmean  = (float*)(wkvt + 512 * 512);  // 8 x 2048 fp32

    prep_kernel<<<4096, 256, 0, stream>>>(queries, keys, pos_table, q_in, k_in, out, hmean);
    wconv_kernel<<<2816, 256, 0, stream>>>(W_Query, W_key, W_Value, fw1, fw2,
                                           wqt, wkt, wvt, fw1t, fw2t, wkp);
    gemm64<<<dim3(8, 8), 256, 0, stream>>>(wvt, wkp, wkvt, 512, 512);
    proj3_kernel<<<dim3(64, 4, 3), 256, 0, stream>>>(q_in, k_in, wqt, wkt, wkvt, qb, kb, vb);
    attn_kernel<<<dim3(64, 4), 512, 0, stream>>>(qb, kb, vb, queries, pos_table,
                                                 key_masks, query_masks, result, out);
    ffn1_mean<<<dim3(64, 16), 256, 0, stream>>>(result, fw1t, hmean);
    ffn2_small<<<dim3(8, 8), 256, 0, stream>>>(hmean, fw2t, out);
}

// Round 11
// 205.787 us; speedup vs baseline: 1.1627x; 1.0062x over previous
//
#include <hip/hip_runtime.h>

// B=8, T=1024, D=512, H=8, dh=64.
// Pipeline: prep(+zero out/hmean) -> wconv -> Wkv^T (gemm64) -> batched q/k/v proj (r8 core) ->
// flash attention (32q/wave = TWO independent 16-q chains SHARING one Ps region -> 58KB LDS ->
// 2 blocks/CU, K/V dbuf, 1 barrier/tile, XCD grid, fused result-mean) -> ffn1 (r8 core) fused
// relu+column-mean -> ffn2 wide.
// LESSONS: r7/r9 — extra per-wave work must be independent AND must not cost residency.
// r10: chains' Ps use is sequential within the wave -> share one region (in-order LDS per wave).

typedef __bf16 bf16x8 __attribute__((ext_vector_type(8)));
typedef __bf16 bf16x4 __attribute__((ext_vector_type(4)));
typedef float f32x4 __attribute__((ext_vector_type(4)));
typedef unsigned short u16x8 __attribute__((ext_vector_type(8)));
typedef unsigned short u16x4 __attribute__((ext_vector_type(4)));

#define MFMA_BF16(a, b, c) __builtin_amdgcn_mfma_f32_16x16x32_bf16((a), (b), (c), 0, 0, 0)
#define NEGBIG (-4294967295.0f)
#define QSCALE 0.18033688011112042f   // 0.125 * log2(e)
#define EXP2(x) __builtin_amdgcn_exp2f(x)

#define GLL16(g, l)                                                                 \
    __builtin_amdgcn_global_load_lds((__attribute__((address_space(1))) void*)(g),  \
                                     (__attribute__((address_space(3))) void*)(l),  \
                                     16, 0, 0)

static __device__ __forceinline__ unsigned short f2bf(float f) {
    __bf16 h = (__bf16)f;
    return __builtin_bit_cast(unsigned short, h);
}
static __device__ __forceinline__ float bf2f(unsigned short h) {
    return __builtin_bit_cast(float, ((unsigned int)h) << 16);
}

// ---------------- prep: q_in/k_in = inputs + pos*sqrt(512); blocks 0-4 also zero out/hmean ---
__global__ __launch_bounds__(256) void prep_kernel(
    const float* __restrict__ q, const float* __restrict__ k,
    const float* __restrict__ pos,
    unsigned short* __restrict__ qo, unsigned short* __restrict__ ko,
    float* __restrict__ out, float* __restrict__ hmean)
{
    if (blockIdx.x < 5) {                      // zero out (4096 f) + hmean (16384 f)
        float* dst = (blockIdx.x == 0) ? out : hmean + (blockIdx.x - 1) * 4096;
        float4 z = {0.f, 0.f, 0.f, 0.f};
#pragma unroll
        for (int j = 0; j < 4; ++j)
            *(float4*)(dst + threadIdx.x * 16 + j * 4) = z;
    }
    size_t i = ((size_t)blockIdx.x * 256 + threadIdx.x) * 4;
    size_t td = i & (size_t)(1024 * 512 - 1);
    float4 qv = *(const float4*)(q + i);
    float4 kv = *(const float4*)(k + i);
    float4 pv = *(const float4*)(pos + td);
    const float S = 22.627416997969522f;
    u16x4 qr, kr;
    qr[0] = f2bf(qv.x + pv.x * S); qr[1] = f2bf(qv.y + pv.y * S);
    qr[2] = f2bf(qv.z + pv.z * S); qr[3] = f2bf(qv.w + pv.w * S);
    kr[0] = f2bf(kv.x + pv.x * S); kr[1] = f2bf(kv.y + pv.y * S);
    kr[2] = f2bf(kv.z + pv.z * S); kr[3] = f2bf(kv.w + pv.w * S);
    *(u16x4*)(qo + i) = qr;
    *(u16x4*)(ko + i) = kr;
}

// ---------------- weight transpose + cast, exact 1D grid (2816 blocks) -----------------------
__global__ __launch_bounds__(256) void wconv_kernel(
    const float* __restrict__ w0, const float* __restrict__ w1, const float* __restrict__ w2,
    const float* __restrict__ w3, const float* __restrict__ w4,
    unsigned short* __restrict__ o0, unsigned short* __restrict__ o1, unsigned short* __restrict__ o2,
    unsigned short* __restrict__ o3, unsigned short* __restrict__ o4,
    unsigned short* __restrict__ wkp)
{
    int id = blockIdx.x;
    const float* in; unsigned short* out; int K, N, kt, nt; bool dup = false;
    if (id < 768) {
        int m = id >> 8; id &= 255;
        in  = (m == 0) ? w0 : ((m == 1) ? w1 : w2);
        out = (m == 0) ? o0 : ((m == 1) ? o1 : o2);
        dup = (m == 1);
        K = 512; N = 512; kt = id >> 4; nt = id & 15;
    } else if (id < 1792) {
        id -= 768; in = w3; out = o3; K = 512; N = 2048; kt = id >> 6; nt = id & 63;
    } else {
        id -= 1792; in = w4; out = o4; K = 2048; N = 512; kt = id >> 4; nt = id & 15;
    }
    int k0 = kt * 32, n0 = nt * 32;
    __shared__ float tile[32][33];
    int tx = threadIdx.x & 31, ty = threadIdx.x >> 5;
#pragma unroll
    for (int i = 0; i < 32; i += 8) {
        float v = in[(size_t)(k0 + ty + i) * N + n0 + tx];
        tile[ty + i][tx] = v;
        if (dup) wkp[(size_t)(k0 + ty + i) * 512 + n0 + tx] = f2bf(v);
    }
    __syncthreads();
#pragma unroll
    for (int i = 0; i < 32; i += 8)
        out[(size_t)(n0 + ty + i) * K + k0 + tx] = f2bf(tile[tx][ty + i]);
}

// ---------------- small GEMM, 64x64 tiles (Wkv^T = Wv^T * Wk): grid (8,8) -------------------
__global__ __launch_bounds__(256) void gemm64(
    const unsigned short* __restrict__ A, const unsigned short* __restrict__ Bt,
    unsigned short* __restrict__ C, int N, int K)
{
    __shared__ unsigned short As[64 * 32];
    __shared__ unsigned short Bs[64 * 32];
    const int tid = threadIdx.x;
    const int wave = tid >> 6, lane = tid & 63;
    const int g = lane >> 4, lr = lane & 15;
    const int wm = (wave >> 1) * 32, wn = (wave & 1) * 32;
    const size_t bm = (size_t)blockIdx.x * 64, bn = (size_t)blockIdx.y * 64;
    const int row = tid >> 2, kc = (tid & 3) * 8;
    const unsigned short* Ap = A + (bm + row) * (size_t)K + kc;
    const unsigned short* Bp = Bt + (bn + row) * (size_t)K + kc;
    unsigned short* AsW = As + tid * 8;
    unsigned short* BsW = Bs + tid * 8;

    f32x4 acc[2][2] = {};
    for (int k0 = 0; k0 < K; k0 += 32) {
        __syncthreads();
        GLL16(Ap + k0, AsW);
        GLL16(Bp + k0, BsW);
        __syncthreads();
        bf16x8 af[2], bfr[2];
#pragma unroll
        for (int t = 0; t < 2; ++t) {
            af[t]  = *(const bf16x8*)&As[(wm + t * 16 + lr) * 32 + g * 8];
            bfr[t] = *(const bf16x8*)&Bs[(wn + t * 16 + lr) * 32 + g * 8];
        }
#pragma unroll
        for (int i = 0; i < 2; ++i)
#pragma unroll
            for (int j = 0; j < 2; ++j)
                acc[i][j] = MFMA_BF16(af[i], bfr[j], acc[i][j]);
    }
#pragma unroll
    for (int i = 0; i < 2; ++i)
#pragma unroll
        for (int j = 0; j < 2; ++j) {
            size_t rr = bm + wm + i * 16 + g * 4;
            size_t cc = bn + wn + j * 16 + lr;
#pragma unroll
            for (int r = 0; r < 4; ++r)
                C[(rr + r) * (size_t)N + cc] = f2bf(acc[i][j][r]);
        }
}

// ---------------- GEMM core (r8): 128x128 tile, BK=64 (two concatenated 128x32 halves) -------
static __device__ __forceinline__ void gemm_core(
    const unsigned short* __restrict__ A,
    const unsigned short* __restrict__ Bt,
    unsigned short* __restrict__ C,
    int N, int K, int mode,
    unsigned short* As, unsigned short* Bs, int bx, int by)
{
    const int tid = threadIdx.x;
    const int wave = tid >> 6, lane = tid & 63;
    const int g = lane >> 4, lr = lane & 15;
    const int wm = (wave >> 1) * 64, wn = (wave & 1) * 64;
    const size_t bm = (size_t)bx * 128, bn = (size_t)by * 128;

    const int srow = tid >> 2, skc = (tid & 3) * 8;
    const unsigned short* Ap = A + (bm + srow) * (size_t)K + skc;
    const unsigned short* Bp = Bt + (bn + srow) * (size_t)K + skc;

    f32x4 acc[4][4] = {};
    for (int k0 = 0; k0 < K; k0 += 64) {
        __syncthreads();
        GLL16(Ap + k0,                        As + tid * 8);
        GLL16(Ap + (size_t)64 * K + k0,       As + 2048 + tid * 8);
        GLL16(Ap + k0 + 32,                   As + 4096 + tid * 8);
        GLL16(Ap + (size_t)64 * K + k0 + 32,  As + 6144 + tid * 8);
        GLL16(Bp + k0,                        Bs + tid * 8);
        GLL16(Bp + (size_t)64 * K + k0,       Bs + 2048 + tid * 8);
        GLL16(Bp + k0 + 32,                   Bs + 4096 + tid * 8);
        GLL16(Bp + (size_t)64 * K + k0 + 32,  Bs + 6144 + tid * 8);
        __syncthreads();
#pragma unroll
        for (int kk = 0; kk < 2; ++kk) {
            bf16x8 af[4], bfr[4];
#pragma unroll
            for (int t = 0; t < 4; ++t) {
                af[t]  = *(const bf16x8*)&As[kk * 4096 + (wm + t * 16 + lr) * 32 + g * 8];
                bfr[t] = *(const bf16x8*)&Bs[kk * 4096 + (wn + t * 16 + lr) * 32 + g * 8];
            }
#pragma unroll
            for (int rt = 0; rt < 4; ++rt)
#pragma unroll
                for (int ct = 0; ct < 4; ++ct)
                    acc[rt][ct] = MFMA_BF16(af[rt], bfr[ct], acc[rt][ct]);
        }
    }

#pragma unroll
    for (int rt = 0; rt < 4; ++rt)
#pragma unroll
        for (int ct = 0; ct < 4; ++ct) {
            size_t row = bm + wm + rt * 16 + g * 4;
            size_t col = bn + wn + ct * 16 + lr;
#pragma unroll
            for (int r = 0; r < 4; ++r) {
                float x = acc[rt][ct][r];
                if (mode == 2) x *= QSCALE;
                C[(row + r) * (size_t)N + col] = f2bf(x);
            }
        }
}

// batched q/k/v projections (v = k_in * Wkv); q output pre-scaled for attention exp2
__global__ __launch_bounds__(256, 2) void proj3_kernel(
    const unsigned short* __restrict__ q_in, const unsigned short* __restrict__ k_in,
    const unsigned short* __restrict__ wqt, const unsigned short* __restrict__ wkt,
    const unsigned short* __restrict__ wkvt,
    unsigned short* __restrict__ qb, unsigned short* __restrict__ kb,
    unsigned short* __restrict__ vb)
{
    __shared__ unsigned short As[128 * 64];
    __shared__ unsigned short Bs[128 * 64];
    const unsigned short *A, *Bt; unsigned short* C; int mode = 0;
    switch (blockIdx.z) {
        case 0:  A = q_in; Bt = wqt;  C = qb; mode = 2; break;
        case 1:  A = k_in; Bt = wkt;  C = kb; break;
        default: A = k_in; Bt = wkvt; C = vb; break;
    }
    gemm_core(A, Bt, C, 512, 512, mode, As, Bs, blockIdx.x, blockIdx.y);
}

// ---------------- ffn1 with fused relu + column-mean: hmean[b][f] += sum_t relu(...) ---------
__global__ __launch_bounds__(256, 2) void ffn1_mean(
    const unsigned short* __restrict__ A,    // result [8192][512]
    const unsigned short* __restrict__ Bt,   // fw1t   [2048][512]
    float* __restrict__ hmean)               // [8][2048]
{
    __shared__ unsigned short As[128 * 64];
    __shared__ unsigned short Bs[128 * 64];
    const int tid = threadIdx.x;
    const int wave = tid >> 6, lane = tid & 63;
    const int g = lane >> 4, lr = lane & 15;
    const int wm = (wave >> 1) * 64, wn = (wave & 1) * 64;
    const size_t bm = (size_t)blockIdx.x * 128, bn = (size_t)blockIdx.y * 128;

    const int srow = tid >> 2, skc = (tid & 3) * 8;
    const unsigned short* Ap = A + (bm + srow) * (size_t)512 + skc;
    const unsigned short* Bp = Bt + (bn + srow) * (size_t)512 + skc;

    f32x4 acc[4][4] = {};
    for (int k0 = 0; k0 < 512; k0 += 64) {
        __syncthreads();
        GLL16(Ap + k0,                         As + tid * 8);
        GLL16(Ap + (size_t)64 * 512 + k0,      As + 2048 + tid * 8);
        GLL16(Ap + k0 + 32,                    As + 4096 + tid * 8);
        GLL16(Ap + (size_t)64 * 512 + k0 + 32, As + 6144 + tid * 8);
        GLL16(Bp + k0,                         Bs + tid * 8);
        GLL16(Bp + (size_t)64 * 512 + k0,      Bs + 2048 + tid * 8);
        GLL16(Bp + k0 + 32,                    Bs + 4096 + tid * 8);
        GLL16(Bp + (size_t)64 * 512 + k0 + 32, Bs + 6144 + tid * 8);
        __syncthreads();
#pragma unroll
        for (int kk = 0; kk < 2; ++kk) {
            bf16x8 af[4], bfr[4];
#pragma unroll
            for (int t = 0; t < 4; ++t) {
                af[t]  = *(const bf16x8*)&As[kk * 4096 + (wm + t * 16 + lr) * 32 + g * 8];
                bfr[t] = *(const bf16x8*)&Bs[kk * 4096 + (wn + t * 16 + lr) * 32 + g * 8];
            }
#pragma unroll
            for (int rt = 0; rt < 4; ++rt)
#pragma unroll
                for (int ct = 0; ct < 4; ++ct)
                    acc[rt][ct] = MFMA_BF16(af[rt], bfr[ct], acc[rt][ct]);
        }
    }

    const int b = blockIdx.x >> 3;
#pragma unroll
    for (int ct = 0; ct < 4; ++ct) {
        float s = 0.f;
#pragma unroll
        for (int rt = 0; rt < 4; ++rt)
#pragma unroll
            for (int r = 0; r < 4; ++r) s += fmaxf(acc[rt][ct][r], 0.f);
        s += __shfl_xor(s, 16, 64);
        s += __shfl_xor(s, 32, 64);
        if (g == 0)
            atomicAdd(hmean + b * 2048 + bn + wn + ct * 16 + lr, s);
    }
}

// ---------------- ffn2 wide: out[b][d] += (1/1024) * sum_f hmean[b][f] * fw2t[d][f] ----------
__global__ __launch_bounds__(256) void ffn2_small(
    const float* __restrict__ hmean, const unsigned short* __restrict__ fw2t,
    float* __restrict__ out)
{
    __shared__ float red[256];
    const int b = blockIdx.x;
    const int d = blockIdx.y * 64 + (threadIdx.x & 63);
    const int fs = (threadIdx.x >> 6) * 512;
    const float* hm = hmean + b * 2048 + fs;
    const unsigned short* wr = fw2t + (size_t)d * 2048 + fs;
    float acc = 0.f;
    for (int f = 0; f < 512; f += 8) {
        u16x8 w = *(const u16x8*)(wr + f);
        f32x4 h0 = *(const f32x4*)(hm + f);
        f32x4 h1 = *(const f32x4*)(hm + f + 4);
        acc += h0[0] * bf2f(w[0]) + h0[1] * bf2f(w[1]) + h0[2] * bf2f(w[2]) + h0[3] * bf2f(w[3])
             + h1[0] * bf2f(w[4]) + h1[1] * bf2f(w[5]) + h1[2] * bf2f(w[6]) + h1[3] * bf2f(w[7]);
    }
    red[threadIdx.x] = acc;
    __syncthreads();
    if (threadIdx.x < 64) {
        float s = red[threadIdx.x] + red[threadIdx.x + 64] +
                  red[threadIdx.x + 128] + red[threadIdx.x + 192];
        out[b * 512 + d] += s * (1.0f / 1024.0f);
    }
}

// ---------------- flash attention: 2 chains/wave SHARING one Ps region, 2 blocks/CU ----------
// grid (64-bh, 4-qtile): x = bh fastest -> (b,h) panel stays on XCD x%8. 256 q/block, 8 waves.
// LDS 58KB: Ks 18K + Vts 18K + Ps 18K (shared between chains: sequential same-wave use,
// in-order LDS per wave makes the overwrite safe) + kbias 4K.
__global__ __launch_bounds__(512, 2) void attn_kernel(
    const unsigned short* __restrict__ Q,     // pre-scaled by QSCALE
    const unsigned short* __restrict__ Kp,
    const unsigned short* __restrict__ V,
    const float* __restrict__ queries,
    const float* __restrict__ pos,
    const float* __restrict__ kmask,
    const float* __restrict__ qmask,
    unsigned short* __restrict__ Res,
    float* __restrict__ out)
{
    __shared__ unsigned short Ks[2][64 * 72];   // [buf][key][d]
    __shared__ unsigned short Vts[2][64 * 72];  // [buf][d][key]
    __shared__ unsigned short Ps[8][16 * 72];   // per-wave P^T, shared by both chains
    __shared__ float kbias[1024];               // additive key-mask bias; reused as red scratch
    const int tid = threadIdx.x, wave = tid >> 6, lane = tid & 63;
    const int g = lane >> 4, lr = lane & 15;
    const int b = blockIdx.x >> 3, h = blockIdx.x & 7;
    const int qg0 = blockIdx.y * 256 + wave * 32 + lr;   // chain u: qg0 + u*16

    for (int i = tid; i < 1024; i += 512)
        kbias[i] = (kmask[b * 1024 + i] == 1.0f) ? 0.f : NEGBIG;

    bf16x8 aq[2][2];
    float qm[2], m_run[2], l_run[2];
    f32x4 o[2][4];
#pragma unroll
    for (int u = 0; u < 2; ++u) {
        const unsigned short* qp = Q + ((size_t)(b * 1024 + qg0 + u * 16)) * 512 + h * 64 + g * 8;
        aq[u][0] = *(const bf16x8*)qp;
        aq[u][1] = *(const bf16x8*)(qp + 32);
        qm[u] = qmask[b * 1024 + qg0 + u * 16];
        m_run[u] = -3.0e38f; l_run[u] = 0.f;
#pragma unroll
        for (int dt = 0; dt < 4; ++dt) o[u][dt] = (f32x4){0.f, 0.f, 0.f, 0.f};
    }

    const unsigned short* kbase = Kp + ((size_t)(b * 1024)) * 512 + h * 64;
    const unsigned short* vbase = V + ((size_t)(b * 1024)) * 512 + h * 64;

    const int half = tid >> 8;                        // 0: V stager, 1: K stager
    const int skey = (tid & 255) >> 2, sd = (tid & 3) * 16;      // K map
    const int vk0 = (tid & 15) * 4, vd0 = ((tid >> 4) & 15) * 4; // V map (key-major lanes)

    u16x8 kr0, kr1; u16x4 vr[4];
    if (half) {
        const unsigned short* kp = kbase + (size_t)skey * 512 + sd;
        kr0 = *(const u16x8*)kp; kr1 = *(const u16x8*)(kp + 8);
    } else {
        const unsigned short* vp = vbase + (size_t)vk0 * 512 + vd0;
#pragma unroll
        for (int j = 0; j < 4; ++j) vr[j] = *(const u16x4*)(vp + (size_t)j * 512);
    }
    if (half) {
        *(u16x8*)&Ks[0][skey * 72 + sd] = kr0;
        *(u16x8*)&Ks[0][skey * 72 + sd + 8] = kr1;
    } else {
#pragma unroll
        for (int i = 0; i < 4; ++i) {
            u16x4 w = { vr[0][i], vr[1][i], vr[2][i], vr[3][i] };
            *(u16x4*)&Vts[0][(vd0 + i) * 72 + vk0] = w;
        }
    }
    if (half) {
        const unsigned short* kp = kbase + (size_t)(64 + skey) * 512 + sd;
        kr0 = *(const u16x8*)kp; kr1 = *(const u16x8*)(kp + 8);
    } else {
        const unsigned short* vp = vbase + (size_t)(64 + vk0) * 512 + vd0;
#pragma unroll
        for (int j = 0; j < 4; ++j) vr[j] = *(const u16x4*)(vp + (size_t)j * 512);
    }
    __syncthreads();

    for (int it = 0; it < 16; ++it) {
        const int j0 = it * 64;
        const unsigned short* Kc = Ks[it & 1];
        const unsigned short* Vc = Vts[it & 1];

        // S^T for both chains first (16 independent MFMAs fill the matrix pipe)
        f32x4 s[2][4];
#pragma unroll
        for (int u = 0; u < 2; ++u)
#pragma unroll
            for (int ct = 0; ct < 4; ++ct) {
                bf16x8 ka = *(const bf16x8*)&Kc[(ct * 16 + lr) * 72 + g * 8];
                bf16x8 kc = *(const bf16x8*)&Kc[(ct * 16 + lr) * 72 + 32 + g * 8];
                f32x4 z = {};
                z = MFMA_BF16(ka, aq[u][0], z);
                s[u][ct] = MFMA_BF16(kc, aq[u][1], z);
            }

        // per-chain: bias, diag, softmax, Ps write, PV; chain 1 reuses Ps after chain 0's reads
#pragma unroll
        for (int u = 0; u < 2; ++u) {
            const int qgu = qg0 + u * 16;
#pragma unroll
            for (int ct = 0; ct < 4; ++ct)
                s[u][ct] += *(const f32x4*)&kbias[j0 + ct * 16 + g * 4];
            if (((qgu ^ j0) & ~63) == 0) {           // wave-uniform diag blinding
#pragma unroll
                for (int ct = 0; ct < 4; ++ct) {
                    unsigned diff = (unsigned)(qgu - (j0 + ct * 16 + g * 4));
                    if (diff < 4u) s[u][ct][diff] = NEGBIG;
                }
            }
            float rmax = -3.0e38f;
#pragma unroll
            for (int ct = 0; ct < 4; ++ct)
#pragma unroll
                for (int r = 0; r < 4; ++r) rmax = fmaxf(rmax, s[u][ct][r]);
            rmax = fmaxf(rmax, __shfl_xor(rmax, 16, 64));
            rmax = fmaxf(rmax, __shfl_xor(rmax, 32, 64));

            float mn = fmaxf(m_run[u], rmax);
            float alpha = EXP2(m_run[u] - mn);
            m_run[u] = mn;
            float psum = 0.f;
#pragma unroll
            for (int ct = 0; ct < 4; ++ct) {
                f32x4 p;
#pragma unroll
                for (int r = 0; r < 4; ++r) { p[r] = EXP2(s[u][ct][r] - mn); psum += p[r]; }
                bf16x4 pk = { (__bf16)p[0], (__bf16)p[1], (__bf16)p[2], (__bf16)p[3] };
                *(bf16x4*)&Ps[wave][lr * 72 + ct * 16 + g * 4] = pk;
            }
            psum += __shfl_xor(psum, 16, 64);
            psum += __shfl_xor(psum, 32, 64);
            l_run[u] = l_run[u] * alpha + psum;
#pragma unroll
            for (int dt = 0; dt < 4; ++dt) o[u][dt] *= alpha;

            bf16x8 p0 = *(const bf16x8*)&Ps[wave][lr * 72 + g * 8];
            bf16x8 p1 = *(const bf16x8*)&Ps[wave][lr * 72 + 32 + g * 8];
#pragma unroll
            for (int dt = 0; dt < 4; ++dt) {
                bf16x8 va = *(const bf16x8*)&Vc[(dt * 16 + lr) * 72 + g * 8];
                bf16x8 vc = *(const bf16x8*)&Vc[(dt * 16 + lr) * 72 + 32 + g * 8];
                o[u][dt] = MFMA_BF16(va, p0, o[u][dt]);
                o[u][dt] = MFMA_BF16(vc, p1, o[u][dt]);
            }
        }

        // store prefetched tile (it+1) into the other buffer; prefetch tile it+2
        if (it + 1 < 16) {
            unsigned short* Kn = Ks[(it + 1) & 1];
            unsigned short* Vn = Vts[(it + 1) & 1];
            if (half) {
                *(u16x8*)&Kn[skey * 72 + sd] = kr0;
                *(u16x8*)&Kn[skey * 72 + sd + 8] = kr1;
            } else {
#pragma unroll
                for (int i = 0; i < 4; ++i) {
                    u16x4 w = { vr[0][i], vr[1][i], vr[2][i], vr[3][i] };
                    *(u16x4*)&Vn[(vd0 + i) * 72 + vk0] = w;
                }
            }
        }
        if (it + 2 < 16) {
            const int jn = (it + 2) * 64;
            if (half) {
                const unsigned short* kp = kbase + (size_t)(jn + skey) * 512 + sd;
                kr0 = *(const u16x8*)kp; kr1 = *(const u16x8*)(kp + 8);
            } else {
                const unsigned short* vp = vbase + (size_t)(jn + vk0) * 512 + vd0;
#pragma unroll
                for (int j = 0; j < 4; ++j) vr[j] = *(const u16x4*)(vp + (size_t)j * 512);
            }
        }
        __syncthreads();                           // single barrier per key-tile
    }

    // epilogue: normalize, query-mask, residual; store Res; fused mean over q
    const float S = 22.627416997969522f;
    float vals[2][4][4];
#pragma unroll
    for (int u = 0; u < 2; ++u) {
        const float inv_l = 1.0f / l_run[u];
        const int qgu = qg0 + u * 16;
#pragma unroll
        for (int dt = 0; dt < 4; ++dt) {
            size_t col = (size_t)h * 64 + dt * 16 + g * 4;
            size_t idx = ((size_t)(b * 1024 + qgu)) * 512 + col;
            f32x4 qv = *(const f32x4*)&queries[idx];
            f32x4 pv = *(const f32x4*)&pos[(size_t)qgu * 512 + col];
            u16x4 wr;
#pragma unroll
            for (int r = 0; r < 4; ++r) {
                float v = o[u][dt][r] * inv_l * qm[u] + qv[r] + pv[r] * S;
                vals[u][dt][r] = v;
                wr[r] = f2bf(v);
            }
            *(u16x4*)&Res[idx] = wr;
        }
    }

    float* red = kbias;                            // kbias reads done (final barrier above)
#pragma unroll
    for (int dt = 0; dt < 4; ++dt)
#pragma unroll
        for (int r = 0; r < 4; ++r) {
            float x = vals[0][dt][r] + vals[1][dt][r];
            x += __shfl_xor(x, 1, 64);
            x += __shfl_xor(x, 2, 64);
            x += __shfl_xor(x, 4, 64);
            x += __shfl_xor(x, 8, 64);
            if (lr == 0) red[wave * 64 + dt * 16 + g * 4 + r] = x;
        }
    __syncthreads();
    if (tid < 64) {
        float s = 0.f;
#pragma unroll
        for (int w = 0; w < 8; ++w) s += red[w * 64 + tid];
        atomicAdd(out + b * 512 + h * 64 + tid, s * (1.0f / 1024.0f));
    }
}

extern "C" void kernel_launch(void* const* d_in, const int* in_sizes, int n_in,
                              void* d_out, int out_size, void* d_ws, size_t ws_size,
                              hipStream_t stream)
{
    (void)in_sizes; (void)n_in; (void)out_size; (void)ws_size;
    const float* queries     = (const float*)d_in[0];
    const float* keys        = (const float*)d_in[1];
    const float* query_masks = (const float*)d_in[2];
    const float* key_masks   = (const float*)d_in[3];
    const float* pos_table   = (const float*)d_in[4];
    const float* W_Query     = (const float*)d_in[5];
    const float* W_key       = (const float*)d_in[6];
    const float* W_Value     = (const float*)d_in[7];
    const float* fw1         = (const float*)d_in[8];
    const float* fw2         = (const float*)d_in[9];
    float* out = (float*)d_out;

    unsigned short* ws = (unsigned short*)d_ws;
    const size_t NE = (size_t)8 * 1024 * 512;
    unsigned short* q_in   = ws;               // -> result after attn
    unsigned short* k_in   = ws + NE;
    unsigned short* qb     = ws + 2 * NE;
    unsigned short* kb     = ws + 3 * NE;
    unsigned short* vb     = ws + 4 * NE;
    unsigned short* result = q_in;
    unsigned short* wqt    = ws + 6 * NE;
    unsigned short* wkt    = wqt + 512 * 512;
    unsigned short* wvt    = wkt + 512 * 512;
    unsigned short* fw1t   = wvt + 512 * 512;     // 2048 x 512
    unsigned short* fw2t   = fw1t + 2048 * 512;   // 512 x 2048
    unsigned short* wkp    = fw2t + 2048 * 512;   // bf16(W_key), plain
    unsigned short* wkvt   = wkp + 512 * 512;     // (Wk*Wv)^T
    float*          hmean  = (float*)(wkvt + 512 * 512);  // 8 x 2048 fp32

    prep_kernel<<<4096, 256, 0, stream>>>(queries, keys, pos_table, q_in, k_in, out, hmean);
    wconv_kernel<<<2816, 256, 0, stream>>>(W_Query, W_key, W_Value, fw1, fw2,
                                           wqt, wkt, wvt, fw1t, fw2t, wkp);
    gemm64<<<dim3(8, 8), 256, 0, stream>>>(wvt, wkp, wkvt, 512, 512);
    proj3_kernel<<<dim3(64, 4, 3), 256, 0, stream>>>(q_in, k_in, wqt, wkt, wkvt, qb, kb, vb);
    attn_kernel<<<dim3(64, 4), 512, 0, stream>>>(qb, kb, vb, queries, pos_table,
                                                 key_masks, query_masks, result, out);
    ffn1_mean<<<dim3(64, 16), 256, 0, stream>>>(result, fw1t, hmean);
    ffn2_small<<<dim3(8, 8), 256, 0, stream>>>(hmean, fw2t, out);
}